// Round 16
// baseline (73.975 us; speedup 1.0000x reference)
//
#include <hip/hip_runtime.h>
#include <math.h>

constexpr int B = 4, C = 64, H = 80, W = 80;
constexpr int HW = H * W;            // 6400
constexpr int NPIX = B * HW;         // 25600
constexpr int PXB = 16;              // pixels per stage1 tile
constexpr int NTILE1 = NPIX / PXB;   // 1600 stage1 tiles
constexpr int GRID1  = 1024;         // persistent blocks = 4/CU wave cap
constexpr int NTILE2 = NPIX / 64;    // 400 m2cv3 tiles

typedef unsigned u32;

static __device__ __forceinline__ float silu(float v) {
    float e = __expf(-v);
    return v * __builtin_amdgcn_rcpf(1.0f + e);
}

// ---- packed u16 helpers (both GLCM channels in one instruction) -----------
static __device__ __forceinline__ u32 pks(u32 a, u32 b){u32 d; asm("v_pk_sub_u16 %0,%1,%2":"=v"(d):"v"(a),"v"(b)); return d;}
static __device__ __forceinline__ u32 pka(u32 a, u32 b){u32 d; asm("v_pk_add_u16 %0,%1,%2":"=v"(d):"v"(a),"v"(b)); return d;}
static __device__ __forceinline__ u32 pkm(u32 a, u32 b){u32 d; asm("v_pk_mul_lo_u16 %0,%1,%2":"=v"(d):"v"(a),"v"(b)); return d;}
static __device__ __forceinline__ u32 pkmin(u32 a, u32 b){u32 d; asm("v_pk_min_u16 %0,%1,%2":"=v"(d):"v"(a),"v"(b)); return d;}
static __device__ __forceinline__ u32 pkmaxi(u32 a, u32 b){u32 d; asm("v_pk_max_i16 %0,%1,%2":"=v"(d):"v"(a),"v"(b)); return d;}
static __device__ __forceinline__ float cb0(u32 a){float f; asm("v_cvt_f32_ubyte0 %0,%1":"=v"(f):"v"(a)); return f;}
static __device__ __forceinline__ float cb2(u32 a){float f; asm("v_cvt_f32_ubyte2 %0,%1":"=v"(f):"v"(a)); return f;}

// byte shuffle/LUT and byte-sum
static __device__ __forceinline__ u32 permb(u32 hi, u32 lo, u32 sel){
    u32 d; asm("v_perm_b32 %0, %1, %2, %3" : "=v"(d) : "v"(hi), "v"(lo), "v"(sel)); return d;}
static __device__ __forceinline__ u32 sad8(u32 a, u32 b, u32 c){
    u32 d; asm("v_sad_u8 %0, %1, %2, %3" : "=v"(d) : "v"(a), "v"(b), "v"(c)); return d;}

// packed compare-exchange: both u16 halves sorted independently (2 channels)
static __device__ __forceinline__ void ce(u32 &x, u32 &y) {
    u32 mn, mx;
    asm("v_pk_min_u16 %0, %2, %3\n\t"
        "v_pk_max_u16 %1, %2, %3"
        : "=&v"(mn), "=v"(mx) : "v"(x), "v"(y));
    x = mn; y = mx;
}

// ---------------------------------------------------------------------------
struct SmA {
    u32   qcell[32][3][18];                            // 6912 B
    float xs[PXB][76] __attribute__((aligned(16)));    // 4864 B
    float ws1[32][68] __attribute__((aligned(16)));    // 8704 B
    float ws2[32][68] __attribute__((aligned(16)));    // 8704 B
    float wsm1[16][32] __attribute__((aligned(16)));   // 2048 B
    float aT[PXB][33];                                 // 2112 B
    float red[8][PXB][4];                              // 2048 B
    int   tile_next;                                   // 4 B
};                                                     // ~35.4 KB -> 4 blk/CU
struct SmB {
    float ys[16][4][82];                               // 20992 B
    float a2[32][64];                                  // 8192 B
    float bs[32][64];                                  // 8192 B
};

static __device__ __forceinline__ void stage_weights(
    SmA& sm, int t,
    const float* __restrict__ w1, const float* __restrict__ w2,
    const float* __restrict__ wm1) {
    const float4* w1f = (const float4*)w1;
    const float4* w2f = (const float4*)w2;
    float4* s1f = (float4*)&sm.ws1[0][0];
    float4* s2f = (float4*)&sm.ws2[0][0];
    for (int e = t; e < 544; e += 512) { s1f[e] = w1f[e]; s2f[e] = w2f[e]; }
    if (t < 128) ((float4*)&sm.wsm1[0][0])[t] = ((const float4*)wm1)[t];
}

static __device__ __forceinline__ void stage1_tile(
    SmA& sm, int t, int tile,
    const float* __restrict__ x,
    const float* __restrict__ s1, const float* __restrict__ b1,
    const float* __restrict__ s2, const float* __restrict__ b2,
    const float* __restrict__ sm1, const float* __restrict__ bm1,
    float* __restrict__ a, float* __restrict__ bbuf, float* __restrict__ y16) {
    const int p0g = tile * PXB;
    const int bb  = p0g / HW;
    const int hw0 = p0g - bb * HW;
    const int h0  = hw0 / W;
    const int c0g = hw0 - h0 * W;

    // ---- A1: quantize stencil cells once, pack both channels ----
    for (int e = t; e < 32 * 3 * 18; e += 512) {
        const int grp = e / 54;
        const int rem = e - grp * 54;
        const int row = rem / 18;
        const int col = rem - row * 18;
        int gr = h0 + row - 1;  gr = gr < 0 ? 0 : (gr > H - 1 ? H - 1 : gr);
        int gc = c0g + col - 1; gc = gc < 0 ? 0 : (gc > W - 1 ? W - 1 : gc);
        const float v0 = x[((size_t)(bb * C + grp * 2)) * HW + gr * W + gc];
        const float v1 = x[((size_t)(bb * C + grp * 2 + 1)) * HW + gr * W + gc];
        int q0 = (int)(v0 * 7.0f); q0 = q0 < 0 ? 0 : (q0 > 7 ? 7 : q0);
        int q1 = (int)(v1 * 7.0f); q1 = q1 < 0 ? 0 : (q1 > 7 ? 7 : q1);
        sm.qcell[grp][row][col] = (u32)q0 | ((u32)q1 << 16);
        if (row == 1 && col >= 1 && col <= 16) {
            sm.xs[col - 1][grp * 2]     = v0;
            sm.xs[col - 1][grp * 2 + 1] = v1;
        }
    }
    __syncthreads();

    // ---- A2: GLCM packed-u16 core (perm/sad LUT for contrast+homog) ----
    const int pxl = t & 15;
    const int grp = t >> 4;
    u32 qpk[9];
    #pragma unroll
    for (int r = 0; r < 3; ++r)
        #pragma unroll
        for (int k = 0; k < 3; ++k)
            qpk[r * 3 + k] = sm.qcell[grp][r][pxl + k];

    static constexpr int PA[20] = {0,1,3,4,6,7, 0,1,2,3,4,5, 0,1,3,4, 1,2,4,5};
    static constexpr int PB[20] = {1,2,4,5,7,8, 3,4,5,6,7,8, 4,5,7,8, 3,4,6,7};

    const u32 ONEpk = 0x00010001u, EIGHTpk = 0x00080008u;
    u32 key[20];
    u32 csI = 0, hloI = 0, hhiI = 0;
    const u32 z0 = 0;
    #pragma unroll
    for (int j = 0; j < 10; ++j) {
        u32 adp0, adp1;
        {
            const u32 qa = qpk[PA[2*j]], qb = qpk[PB[2*j]];
            const u32 d = pks(qa, qb);
            adp0 = pkmaxi(d, pks(0u, d));
            key[2*j] = pka(pkm(qa, EIGHTpk), qb);
        }
        {
            const u32 qa = qpk[PA[2*j+1]], qb = qpk[PB[2*j+1]];
            const u32 d = pks(qa, qb);
            adp1 = pkmaxi(d, pks(0u, d));
            key[2*j+1] = pka(pkm(qa, EIGHTpk), qb);
        }
        const u32 pk4 = permb(adp1, adp0, 0x06040200u);
        csI  = sad8(permb(0x31241910u, 0x09040100u, pk4), z0, csI);
        hloI = sad8(permb(0x69788CA8u, 0xD218A448u, pk4), z0, hloI);
        hhiI = sad8(permb(0x00000000u, 0x00010103u, pk4), z0, hhiI);
    }

    #pragma unroll
    for (int p = 1; p < 32; p <<= 1) {
        #pragma unroll
        for (int k = p; k >= 1; k >>= 1) {
            const int jm = k % p;
            #pragma unroll
            for (int lo = 0; lo < 20; ++lo) {
                const int hi = lo + k;
                if (hi < 20 && lo >= jm && ((lo - jm) % (2 * k)) < k &&
                    (lo / (2 * p)) == (hi / (2 * p))) {
                    ce(key[lo], key[hi]);
                }
            }
        }
    }

    u32 eq[20];
    #pragma unroll
    for (int ai = 1; ai < 20; ++ai)
        eq[ai] = pks(ONEpk, pkmin(pks(key[ai], key[ai - 1]), ONEpk));

    u32 pc = 0, ps = 0, pv[20];
    pv[0] = 0;
    #pragma unroll
    for (int ai = 1; ai < 20; ++ai) {
        pc = pkm(pka(pc, ONEpk), eq[ai]);
        pv[ai] = pc;
        ps = pka(ps, pc);
    }
    float pr0, pr1;
    {
        const u32 m = pka(pv[19], ONEpk);
        pr0 = cb0(m); pr1 = cb2(m);
    }
    u32 rc = 0;
    #pragma unroll
    for (int ai = 18; ai >= 0; --ai) {
        rc = pkm(pka(rc, ONEpk), eq[ai + 1]);
        const u32 m = pka(pka(pv[ai], rc), ONEpk);
        pr0 *= cb0(m); pr1 *= cb2(m);
    }

    const int psum = (int)(ps & 0xFFFFu) + (int)(ps >> 16);
    const float lsum = __logf(pr0) + __logf(pr1);

    float fc = (float)csI * (1.f / 20.f);
    float fe = ((float)psum * 2.f + 40.f) * (1.f / 400.f);
    float fn = -(lsum + 40.f * -2.9957322736f) * (1.f / 20.f);
    float fh = (float)(hloI + (hhiI << 8)) * (1.f / 16800.f);

    fc += __shfl_xor(fc, 16); fe += __shfl_xor(fe, 16);
    fn += __shfl_xor(fn, 16); fh += __shfl_xor(fh, 16);
    fc += __shfl_xor(fc, 32); fe += __shfl_xor(fe, 32);
    fn += __shfl_xor(fn, 32); fh += __shfl_xor(fh, 32);
    const int wv = t >> 6;
    if ((t & 63) < 16) {
        sm.red[wv][pxl][0] = fc; sm.red[wv][pxl][1] = fe;
        sm.red[wv][pxl][2] = fn; sm.red[wv][pxl][3] = fh;
    }
    __syncthreads();
    if (t < 64) {
        const int p2 = t >> 2, f = t & 3;
        float s = 0.f;
        #pragma unroll
        for (int wq = 0; wq < 8; ++wq) s += sm.red[wq][p2][f];
        sm.xs[p2][64 + f] = s * (1.f / 64.f);
    }
    __syncthreads();

    // ---- A3: cv1 + cv2, thread = (px, oc); float4 LDS reads ----
    {
        const int px = t & 15;
        const int oc = t >> 4;
        float acc1 = 0.f, acc2 = 0.f;
        #pragma unroll
        for (int k = 0; k < 17; ++k) {
            const float4 xv = *reinterpret_cast<const float4*>(&sm.xs[px][k * 4]);
            const float4 wa = *reinterpret_cast<const float4*>(&sm.ws1[oc][k * 4]);
            const float4 wb = *reinterpret_cast<const float4*>(&sm.ws2[oc][k * 4]);
            acc1 += xv.x * wa.x + xv.y * wa.y + xv.z * wa.z + xv.w * wa.w;
            acc2 += xv.x * wb.x + xv.y * wb.y + xv.z * wb.z + xv.w * wb.w;
        }
        const int hw2 = hw0 + px;
        const float v1 = silu(acc1 * s1[oc] + b1[oc]);
        a[((size_t)(bb * 32 + oc)) * HW + hw2] = v1;
        sm.aT[px][oc] = v1;
        bbuf[((size_t)(bb * 32 + oc)) * HW + hw2] = silu(acc2 * s2[oc] + b2[oc]);
    }
    __syncthreads();

    // ---- A4: m1, thread = (px, oc16), first 256 threads ----
    if (t < 256) {
        const int px = t & 15;
        const int oc = t >> 4;
        float acc = 0.f;
        #pragma unroll 8
        for (int ic = 0; ic < 32; ++ic)
            acc += sm.aT[px][ic] * sm.wsm1[oc][ic];
        y16[((size_t)(bb * 16 + oc)) * HW + hw0 + px] = silu(acc * sm1[oc] + bm1[oc]);
    }
}

// ---------------------------------------------------------------------------
// Kernel 1: persistent blocks + DYNAMIC work queue (atomicAdd tile counter).
// R15 lesson: static 2-tile assignment (800 blocks) had a 1.28x imbalance
// (32 CUs x 8 tile-latencies vs 224 x 6). The queue reproduces hardware
// backfill's self-balancing while staging weights once per block and
// removing per-block launch overhead. No inter-block dependency -> blocks
// that never become resident just see tile>=NTILE1 and exit (no deadlock,
// unlike the abandoned coop-fusion line of R13/R14).
// ---------------------------------------------------------------------------
__global__ __launch_bounds__(512, 4) void stage1_kernel(
    const float* __restrict__ x,
    const float* __restrict__ w1, const float* __restrict__ s1, const float* __restrict__ b1,
    const float* __restrict__ w2, const float* __restrict__ s2, const float* __restrict__ b2,
    const float* __restrict__ wm1, const float* __restrict__ sm1, const float* __restrict__ bm1,
    float* __restrict__ a, float* __restrict__ bbuf, float* __restrict__ y16,
    int* __restrict__ ctr) {
    __shared__ SmA sm;
    const int t = threadIdx.x;
    stage_weights(sm, t, w1, w2, wm1);
    for (;;) {
        if (t == 0) sm.tile_next = atomicAdd(ctr, 1);
        __syncthreads();                  // publish tile; also fences prev A4
        const int tile = sm.tile_next;
        if (tile >= NTILE1) break;        // uniform exit
        stage1_tile(sm, t, tile, x, s1, b1, s2, b2, sm1, bm1, a, bbuf, y16);
    }
}

// ---------------------------------------------------------------------------
// Kernel 2: m2 (3x3, 16->32, pad 1) + BN + SiLU + residual, then cv3
// (1x1, 64->64). R11's proven 8-wave structure, 400 blocks. Unchanged.
// ---------------------------------------------------------------------------
__global__ __launch_bounds__(512, 4) void m2cv3_kernel(
    const float* __restrict__ y16, const float* __restrict__ a,
    const float* __restrict__ bbuf,
    const float* __restrict__ wm2, const float* __restrict__ sm2, const float* __restrict__ bm2,
    const float* __restrict__ wc, const float* __restrict__ sc, const float* __restrict__ bc,
    float* __restrict__ out) {
    __shared__ SmB sm;
    const int t = threadIdx.x;
    const int p0 = blockIdx.x * 64;
    const int bi = p0 / HW;
    const int hw0 = p0 - bi * HW;
    const int h0 = hw0 / W;

    const float* yb = y16 + (size_t)(bi * 16) * HW;
    for (int e = t; e < 16 * 4 * 82; e += 512) {
        const int ch = e / 328;
        const int rem = e - ch * 328;
        const int row = rem / 82;
        const int col = rem - row * 82;
        const int r = h0 - 1 + row;
        const int c = col - 1;
        float v = 0.f;
        if ((unsigned)r < (unsigned)H && (unsigned)c < (unsigned)W)
            v = yb[(size_t)ch * HW + r * W + c];
        sm.ys[ch][row][col] = v;
    }
    for (int e = t; e < 32 * 64; e += 512) {
        const int ic = e >> 6, px = e & 63;
        sm.bs[ic][px] = bbuf[((size_t)(bi * 32 + ic)) * HW + hw0 + px];
    }
    __syncthreads();

    const int lane = t & 63;
    const int wv = __builtin_amdgcn_readfirstlane(t >> 6);
    const int hw = hw0 + lane;
    const int h = hw / W;
    const int w = hw - h * W;
    const int lr = h - h0;
    const int oc0 = wv * 4;

    float acc[4] = {0.f, 0.f, 0.f, 0.f};
    #pragma unroll 2
    for (int ic = 0; ic < 16; ++ic) {
        #pragma unroll
        for (int ky = 0; ky < 3; ++ky) {
            #pragma unroll
            for (int kx = 0; kx < 3; ++kx) {
                const float v = sm.ys[ic][lr + ky][w + kx];
                const int tap = ic * 9 + ky * 3 + kx;
                #pragma unroll
                for (int j = 0; j < 4; ++j)
                    acc[j] += v * wm2[(oc0 + j) * 144 + tap];
            }
        }
    }
    #pragma unroll
    for (int j = 0; j < 4; ++j) {
        const int oc = oc0 + j;
        sm.a2[oc][lane] = a[((size_t)(bi * 32 + oc)) * HW + hw]
                        + silu(acc[j] * sm2[oc] + bm2[oc]);
    }
    __syncthreads();
    const int oc3 = wv * 8;
    float c_[8] = {0.f, 0.f, 0.f, 0.f, 0.f, 0.f, 0.f, 0.f};
    #pragma unroll 4
    for (int ic = 0; ic < 32; ++ic) {
        const float av = sm.a2[ic][lane];
        const float bv = sm.bs[ic][lane];
        #pragma unroll
        for (int j = 0; j < 8; ++j) {
            c_[j] += av * wc[(oc3 + j) * 64 + ic];
            c_[j] += bv * wc[(oc3 + j) * 64 + 32 + ic];
        }
    }
    #pragma unroll
    for (int j = 0; j < 8; ++j) {
        const int oc = oc3 + j;
        out[((size_t)(bi * 64 + oc)) * HW + hw] = silu(c_[j] * sc[oc] + bc[oc]);
    }
}

// ---------------------------------------------------------------------------
extern "C" void kernel_launch(void* const* d_in, const int* in_sizes, int n_in,
                              void* d_out, int out_size, void* d_ws, size_t ws_size,
                              hipStream_t stream) {
    const float* x    = (const float*)d_in[0];
    const float* cv1w = (const float*)d_in[1];
    const float* cv1s = (const float*)d_in[2];
    const float* cv1b = (const float*)d_in[3];
    const float* cv2w = (const float*)d_in[4];
    const float* cv2s = (const float*)d_in[5];
    const float* cv2b = (const float*)d_in[6];
    const float* m1w  = (const float*)d_in[7];
    const float* m1s  = (const float*)d_in[8];
    const float* m1b  = (const float*)d_in[9];
    const float* m2w  = (const float*)d_in[10];
    const float* m2s  = (const float*)d_in[11];
    const float* m2b  = (const float*)d_in[12];
    const float* cv3w = (const float*)d_in[13];
    const float* cv3s = (const float*)d_in[14];
    const float* cv3b = (const float*)d_in[15];

    float* ws   = (float*)d_ws;
    float* a    = ws;                 // 4*32*6400 = 819200
    float* bbuf = ws + 819200;        // 819200
    float* y16  = ws + 1638400;       // 409600 (end 2048000)
    int*   ctr  = (int*)(ws + 2048000);

    hipMemsetAsync(ctr, 0, sizeof(int), stream);   // reset queue each call
    stage1_kernel<<<GRID1, 512, 0, stream>>>(
        x, cv1w, cv1s, cv1b, cv2w, cv2s, cv2b, m1w, m1s, m1b,
        a, bbuf, y16, ctr);
    m2cv3_kernel<<<NTILE2, 512, 0, stream>>>(
        y16, a, bbuf, m2w, m2s, m2b, cv3w, cv3s, cv3b, (float*)d_out);
}

// Round 17
// 56.031 us; speedup vs baseline: 1.3202x; 1.3202x over previous
//
#include <hip/hip_runtime.h>
#include <math.h>

constexpr int B = 4, C = 64, H = 80, W = 80;
constexpr int HW = H * W;            // 6400
constexpr int NPIX = B * HW;         // 25600
constexpr int PXB = 16;              // pixels per block (16 | W=80)
constexpr int NTILE1 = NPIX / PXB;   // 1600 stage1 blocks (plain launch —
                                     // R13-R16: every alternative regressed)
constexpr int NTILE2 = NPIX / 64;    // 400 m2cv3 blocks

typedef unsigned u32;
typedef float f32x2 __attribute__((ext_vector_type(2)));

static __device__ __forceinline__ float silu(float v) {
    float e = __expf(-v);
    return v * __builtin_amdgcn_rcpf(1.0f + e);
}

// ---- packed u16 helpers (both GLCM channels in one instruction) -----------
static __device__ __forceinline__ u32 pks(u32 a, u32 b){u32 d; asm("v_pk_sub_u16 %0,%1,%2":"=v"(d):"v"(a),"v"(b)); return d;}
static __device__ __forceinline__ u32 pka(u32 a, u32 b){u32 d; asm("v_pk_add_u16 %0,%1,%2":"=v"(d):"v"(a),"v"(b)); return d;}
static __device__ __forceinline__ u32 pkm(u32 a, u32 b){u32 d; asm("v_pk_mul_lo_u16 %0,%1,%2":"=v"(d):"v"(a),"v"(b)); return d;}
static __device__ __forceinline__ u32 pkmin(u32 a, u32 b){u32 d; asm("v_pk_min_u16 %0,%1,%2":"=v"(d):"v"(a),"v"(b)); return d;}
static __device__ __forceinline__ u32 pkmaxi(u32 a, u32 b){u32 d; asm("v_pk_max_i16 %0,%1,%2":"=v"(d):"v"(a),"v"(b)); return d;}
static __device__ __forceinline__ float cb0(u32 a){float f; asm("v_cvt_f32_ubyte0 %0,%1":"=v"(f):"v"(a)); return f;}
static __device__ __forceinline__ float cb2(u32 a){float f; asm("v_cvt_f32_ubyte2 %0,%1":"=v"(f):"v"(a)); return f;}

// byte shuffle/LUT and byte-sum
static __device__ __forceinline__ u32 permb(u32 hi, u32 lo, u32 sel){
    u32 d; asm("v_perm_b32 %0, %1, %2, %3" : "=v"(d) : "v"(hi), "v"(lo), "v"(sel)); return d;}
static __device__ __forceinline__ u32 sad8(u32 a, u32 b, u32 c){
    u32 d; asm("v_sad_u8 %0, %1, %2, %3" : "=v"(d) : "v"(a), "v"(b), "v"(c)); return d;}

// packed compare-exchange: both u16 halves sorted independently (2 channels)
static __device__ __forceinline__ void ce(u32 &x, u32 &y) {
    u32 mn, mx;
    asm("v_pk_min_u16 %0, %2, %3\n\t"
        "v_pk_max_u16 %1, %2, %3"
        : "=&v"(mn), "=v"(mx) : "v"(x), "v"(y));
    x = mn; y = mx;
}

// ---------------------------------------------------------------------------
// Kernel 1: GLCM + cv1 + cv2 + m1 fused. block 512 = 16 px x 32 ch-pairs.
// = the 58.5-µs best build (perm/sad LUT) + three instruction-level edits:
//  (1) global stores of a/bbuf DEFERRED past the A3->A4 barrier (barrier
//      no longer drains vmcnt for stores — guide §5 barrier-drain).
//  (2) conv accumulation as plain-C f32x2 -> compiler emits v_pk_fma_f32
//      (R10's regression was asm "+v" serialization, not the pk concept).
//  (3) xs stride 72->76 (72%32=8: px {0,4,8,12} aliased -> 4-way conflict
//      on A3's b128 reads; 76%32=12 -> free 2-way). aT 33->34 for b64 align.
// ---------------------------------------------------------------------------
__global__ __launch_bounds__(512, 4) void glcm_stage1_kernel(
    const float* __restrict__ x,
    const float* __restrict__ w1, const float* __restrict__ s1, const float* __restrict__ b1,
    const float* __restrict__ w2, const float* __restrict__ s2, const float* __restrict__ b2,
    const float* __restrict__ wm1, const float* __restrict__ sm1, const float* __restrict__ bm1,
    float* __restrict__ a, float* __restrict__ bbuf, float* __restrict__ y16) {
    __shared__ u32 qcell[32][3][18];              // packed quantized stencil rows
    __shared__ __align__(16) float xs[PXB][76];   // [px][68 ic + 4 g], pad 76
    __shared__ __align__(16) float ws1[32][68];   // cv1 weights, natural layout
    __shared__ __align__(16) float ws2[32][68];
    __shared__ __align__(16) float wsm1[16][32];
    __shared__ __align__(16) float aT[PXB][34];   // cv1 out tile (b64-aligned)
    __shared__ float red[8][PXB][4];

    const int t = threadIdx.x;
    const int p0g = blockIdx.x * PXB;
    const int bb  = p0g / HW;
    const int hw0 = p0g - bb * HW;
    const int h0  = hw0 / W;
    const int c0g = hw0 - h0 * W;        // col base (block is 16 px in one row)

    // ---- phase 0a: weights -> LDS (float4 linear copies) ----
    {
        const float4* w1f = (const float4*)w1;
        const float4* w2f = (const float4*)w2;
        float4* s1f = (float4*)&ws1[0][0];
        float4* s2f = (float4*)&ws2[0][0];
        for (int e = t; e < 544; e += 512) { s1f[e] = w1f[e]; s2f[e] = w2f[e]; }
        if (t < 128) ((float4*)&wsm1[0][0])[t] = ((const float4*)wm1)[t];
    }
    // ---- phase 0b: quantize stencil rows once, pack both channels ----
    for (int e = t; e < 32 * 3 * 18; e += 512) {
        const int grp = e / 54;
        const int rem = e - grp * 54;
        const int row = rem / 18;        // 0..2  (image rows h0-1..h0+1, clamped)
        const int col = rem - row * 18;  // 0..17 (image cols c0g-1..c0g+16, clamped)
        int gr = h0 + row - 1;  gr = gr < 0 ? 0 : (gr > H - 1 ? H - 1 : gr);
        int gc = c0g + col - 1; gc = gc < 0 ? 0 : (gc > W - 1 ? W - 1 : gc);
        const float v0 = x[((size_t)(bb * C + grp * 2)) * HW + gr * W + gc];
        const float v1 = x[((size_t)(bb * C + grp * 2 + 1)) * HW + gr * W + gc];
        int q0 = (int)(v0 * 7.0f); q0 = q0 < 0 ? 0 : (q0 > 7 ? 7 : q0);
        int q1 = (int)(v1 * 7.0f); q1 = q1 < 0 ? 0 : (q1 > 7 ? 7 : q1);
        qcell[grp][row][col] = (u32)q0 | ((u32)q1 << 16);
        if (row == 1 && col >= 1 && col <= 16) {   // raw centers for the convs
            xs[col - 1][grp * 2]     = v0;
            xs[col - 1][grp * 2 + 1] = v1;
        }
    }
    __syncthreads();

    // ---- phase 1: GLCM (packed-u16 core; 9 LDS reads, zero quantize) ----
    const int pxl = t & 15;              // 0..15
    const int grp = t >> 4;              // 0..31 (channel pair)
    u32 qpk[9];
    #pragma unroll
    for (int r = 0; r < 3; ++r)
        #pragma unroll
        for (int k = 0; k < 3; ++k)
            qpk[r * 3 + k] = qcell[grp][r][pxl + k];

    static constexpr int PA[20] = {0,1,3,4,6,7, 0,1,2,3,4,5, 0,1,3,4, 1,2,4,5};
    static constexpr int PB[20] = {1,2,4,5,7,8, 3,4,5,6,7,8, 4,5,7,8, 3,4,6,7};

    const u32 ONEpk = 0x00010001u, EIGHTpk = 0x00080008u;
    u32 key[20];
    u32 csI = 0, hloI = 0, hhiI = 0;     // integer byte-sums (both channels)
    const u32 z0 = 0;
    #pragma unroll
    for (int j = 0; j < 10; ++j) {
        u32 adp0, adp1;
        {
            const u32 qa = qpk[PA[2*j]], qb = qpk[PB[2*j]];
            const u32 d = pks(qa, qb);
            adp0 = pkmaxi(d, pks(0u, d));              // |d| per half, 0..7
            key[2*j] = pka(pkm(qa, EIGHTpk), qb);      // qa*8+qb per half
        }
        {
            const u32 qa = qpk[PA[2*j+1]], qb = qpk[PB[2*j+1]];
            const u32 d = pks(qa, qb);
            adp1 = pkmaxi(d, pks(0u, d));
            key[2*j+1] = pka(pkm(qa, EIGHTpk), qb);
        }
        // pack 4 |d| bytes: {adp0.ch0, adp0.ch1, adp1.ch0, adp1.ch1}
        const u32 pk4 = permb(adp1, adp0, 0x06040200u);
        // d^2 LUT {0,1,4,9 | 16,25,36,49}; byte-sum via sad
        csI  = sad8(permb(0x31241910u, 0x09040100u, pk4), z0, csI);
        // 840/(1+|d|) = {840,420,280,210,168,140,120,105}: lo/hi byte LUTs
        hloI = sad8(permb(0x69788CA8u, 0xD218A448u, pk4), z0, hloI);
        hhiI = sad8(permb(0x00000000u, 0x00010103u, pk4), z0, hhiI);
    }

    // Batcher odd-even mergesort for n=32, pruned to the low 20 slots
    #pragma unroll
    for (int p = 1; p < 32; p <<= 1) {
        #pragma unroll
        for (int k = p; k >= 1; k >>= 1) {
            const int jm = k % p;
            #pragma unroll
            for (int lo = 0; lo < 20; ++lo) {
                const int hi = lo + k;
                if (hi < 20 && lo >= jm && ((lo - jm) % (2 * k)) < k &&
                    (lo / (2 * p)) == (hi / (2 * p))) {
                    ce(key[lo], key[hi]);
                }
            }
        }
    }

    // boundary flags: eq[a] = (key[a]==key[a-1]) per half as 0/1 (packed)
    u32 eq[20];
    #pragma unroll
    for (int ai = 1; ai < 20; ++ai)
        eq[ai] = pks(ONEpk, pkmin(pks(key[ai], key[ai - 1]), ONEpk));

    // forward run scan: pc = (pc+1)*eq  (packed), psum += pc
    u32 pc = 0, ps = 0, pv[20];
    pv[0] = 0;
    #pragma unroll
    for (int ai = 1; ai < 20; ++ai) {
        pc = pkm(pka(pc, ONEpk), eq[ai]);
        pv[ai] = pc;
        ps = pka(ps, pc);
    }
    // backward run scan + multiplicity product: m = p + r + 1 (<=20, byte)
    float pr0, pr1;
    {
        const u32 m = pka(pv[19], ONEpk);
        pr0 = cb0(m); pr1 = cb2(m);
    }
    u32 rc = 0;
    #pragma unroll
    for (int ai = 18; ai >= 0; --ai) {
        rc = pkm(pka(rc, ONEpk), eq[ai + 1]);
        const u32 m = pka(pka(pv[ai], rc), ONEpk);
        pr0 *= cb0(m); pr1 *= cb2(m);
    }

    const int psum = (int)(ps & 0xFFFFu) + (int)(ps >> 16);
    const float lsum = __logf(pr0) + __logf(pr1);

    float fc = (float)csI * (1.f / 20.f);                // contrast (both ch)
    float fe = ((float)psum * 2.f + 40.f) * (1.f / 400.f);
    float fn = -(lsum + 40.f * -2.9957322736f) * (1.f / 20.f);
    float fh = (float)(hloI + (hhiI << 8)) * (1.f / 16800.f);  // /840/20

    // reduce over 4 ch-pairs within the wave (lane bits 4,5), then 8 waves
    fc += __shfl_xor(fc, 16); fe += __shfl_xor(fe, 16);
    fn += __shfl_xor(fn, 16); fh += __shfl_xor(fh, 16);
    fc += __shfl_xor(fc, 32); fe += __shfl_xor(fe, 32);
    fn += __shfl_xor(fn, 32); fh += __shfl_xor(fh, 32);
    const int wv = t >> 6;               // 0..7
    if ((t & 63) < 16) {
        red[wv][pxl][0] = fc; red[wv][pxl][1] = fe;
        red[wv][pxl][2] = fn; red[wv][pxl][3] = fh;
    }
    __syncthreads();
    if (t < 64) {
        const int p2 = t >> 2, f = t & 3;
        float s = 0.f;
        #pragma unroll
        for (int wq = 0; wq < 8; ++wq) s += red[wq][p2][f];
        xs[p2][64 + f] = s * (1.f / 64.f);   // g appended to xs in LDS
    }
    __syncthreads();   // xs (x centers + g) complete

    // ---- phase 2: cv1 + cv2, thread = (px, oc). float4 LDS reads, f32x2
    //      accumulation (compiler -> v_pk_fma_f32). Global stores DEFERRED. ----
    const int px = t & 15;
    const int oc = t >> 4;               // 0..31
    float v1out, v2out;
    {
        f32x2 a1l = {0.f, 0.f}, a1h = {0.f, 0.f};
        f32x2 a2l = {0.f, 0.f}, a2h = {0.f, 0.f};
        #pragma unroll
        for (int k = 0; k < 17; ++k) {
            const float4 xv = *reinterpret_cast<const float4*>(&xs[px][k * 4]);
            const float4 wa = *reinterpret_cast<const float4*>(&ws1[oc][k * 4]);
            const float4 wb = *reinterpret_cast<const float4*>(&ws2[oc][k * 4]);
            const f32x2 xl = {xv.x, xv.y}, xh = {xv.z, xv.w};
            a1l += xl * (f32x2){wa.x, wa.y};
            a1h += xh * (f32x2){wa.z, wa.w};
            a2l += xl * (f32x2){wb.x, wb.y};
            a2h += xh * (f32x2){wb.z, wb.w};
        }
        const float acc1 = a1l.x + a1l.y + a1h.x + a1h.y;
        const float acc2 = a2l.x + a2l.y + a2h.x + a2h.y;
        v1out = silu(acc1 * s1[oc] + b1[oc]);
        v2out = silu(acc2 * s2[oc] + b2[oc]);
        aT[px][oc] = v1out;              // LDS only before the barrier
    }
    __syncthreads();                     // drains lgkm only (no global stores)

    // ---- phase 3: m1 (f32x2), thread = (px, oc16), first 256 threads ----
    float ymout = 0.f;
    if (t < 256) {
        const int oc16 = t >> 4;
        f32x2 A = {0.f, 0.f};
        #pragma unroll
        for (int k = 0; k < 16; ++k) {
            const f32x2 av = *reinterpret_cast<const f32x2*>(&aT[px][k * 2]);
            const f32x2 wv2 = *reinterpret_cast<const f32x2*>(&wsm1[oc16][k * 2]);
            A += av * wv2;
        }
        ymout = silu((A.x + A.y) * sm1[oc16] + bm1[oc16]);
    }

    // ---- deferred global stores (drain at kernel end, not at a barrier) ----
    {
        const int hw2 = hw0 + px;
        a[((size_t)(bb * 32 + oc)) * HW + hw2]    = v1out;
        bbuf[((size_t)(bb * 32 + oc)) * HW + hw2] = v2out;
        if (t < 256)
            y16[((size_t)(bb * 16 + (t >> 4))) * HW + hw2] = ymout;
    }
}

// ---------------------------------------------------------------------------
// Kernel 2: m2 (3x3, 16->32, pad 1) + BN + SiLU + residual, then cv3
// (1x1, 64->64). The proven 512-thread 8-wave structure (58.5-µs build).
// ---------------------------------------------------------------------------
__global__ __launch_bounds__(512) void m2cv3_kernel(
    const float* __restrict__ y16, const float* __restrict__ a,
    const float* __restrict__ bbuf,
    const float* __restrict__ wm2, const float* __restrict__ sm2, const float* __restrict__ bm2,
    const float* __restrict__ wc, const float* __restrict__ sc, const float* __restrict__ bc,
    float* __restrict__ out) {
    __shared__ float ys[16][4][82];
    __shared__ float a2[32][64];
    __shared__ float bs[32][64];
    const int t = threadIdx.x;
    const int p0 = blockIdx.x * 64;
    const int bi = p0 / HW;
    const int hw0 = p0 - bi * HW;
    const int h0 = hw0 / W;

    const float* yb = y16 + (size_t)(bi * 16) * HW;
    for (int e = t; e < 16 * 4 * 82; e += 512) {
        const int ch = e / 328;
        const int rem = e - ch * 328;
        const int row = rem / 82;
        const int col = rem - row * 82;
        const int r = h0 - 1 + row;
        const int c = col - 1;
        float v = 0.f;
        if ((unsigned)r < (unsigned)H && (unsigned)c < (unsigned)W)
            v = yb[(size_t)ch * HW + r * W + c];
        ys[ch][row][col] = v;
    }
    for (int e = t; e < 32 * 64; e += 512) {
        const int ic = e >> 6, px = e & 63;
        bs[ic][px] = bbuf[((size_t)(bi * 32 + ic)) * HW + hw0 + px];
    }
    __syncthreads();

    const int lane = t & 63;
    const int wv = __builtin_amdgcn_readfirstlane(t >> 6);
    const int hw = hw0 + lane;
    const int h = hw / W;
    const int w = hw - h * W;
    const int lr = h - h0;
    const int oc0 = wv * 4;

    float acc[4] = {0.f, 0.f, 0.f, 0.f};
    #pragma unroll 2
    for (int ic = 0; ic < 16; ++ic) {
        #pragma unroll
        for (int ky = 0; ky < 3; ++ky) {
            #pragma unroll
            for (int kx = 0; kx < 3; ++kx) {
                const float v = ys[ic][lr + ky][w + kx];
                const int tap = ic * 9 + ky * 3 + kx;
                #pragma unroll
                for (int j = 0; j < 4; ++j)
                    acc[j] += v * wm2[(oc0 + j) * 144 + tap];
            }
        }
    }
    #pragma unroll
    for (int j = 0; j < 4; ++j) {
        const int oc = oc0 + j;
        a2[oc][lane] = a[((size_t)(bi * 32 + oc)) * HW + hw]
                     + silu(acc[j] * sm2[oc] + bm2[oc]);
    }
    __syncthreads();
    const int oc3 = wv * 8;
    float c_[8] = {0.f, 0.f, 0.f, 0.f, 0.f, 0.f, 0.f, 0.f};
    #pragma unroll 4
    for (int ic = 0; ic < 32; ++ic) {
        const float av = a2[ic][lane];
        const float bv = bs[ic][lane];
        #pragma unroll
        for (int j = 0; j < 8; ++j) {
            c_[j] += av * wc[(oc3 + j) * 64 + ic];
            c_[j] += bv * wc[(oc3 + j) * 64 + 32 + ic];
        }
    }
    #pragma unroll
    for (int j = 0; j < 8; ++j) {
        const int oc = oc3 + j;
        out[((size_t)(bi * 64 + oc)) * HW + hw] = silu(c_[j] * sc[oc] + bc[oc]);
    }
}

// ---------------------------------------------------------------------------
extern "C" void kernel_launch(void* const* d_in, const int* in_sizes, int n_in,
                              void* d_out, int out_size, void* d_ws, size_t ws_size,
                              hipStream_t stream) {
    const float* x    = (const float*)d_in[0];
    const float* cv1w = (const float*)d_in[1];
    const float* cv1s = (const float*)d_in[2];
    const float* cv1b = (const float*)d_in[3];
    const float* cv2w = (const float*)d_in[4];
    const float* cv2s = (const float*)d_in[5];
    const float* cv2b = (const float*)d_in[6];
    const float* m1w  = (const float*)d_in[7];
    const float* m1s  = (const float*)d_in[8];
    const float* m1b  = (const float*)d_in[9];
    const float* m2w  = (const float*)d_in[10];
    const float* m2s  = (const float*)d_in[11];
    const float* m2b  = (const float*)d_in[12];
    const float* cv3w = (const float*)d_in[13];
    const float* cv3s = (const float*)d_in[14];
    const float* cv3b = (const float*)d_in[15];

    float* ws   = (float*)d_ws;
    float* a    = ws;                 // 4*32*6400 = 819200
    float* bbuf = ws + 819200;        // 819200
    float* y16  = ws + 1638400;       // 409600 (end 2048000)

    glcm_stage1_kernel<<<NTILE1, 512, 0, stream>>>(
        x, cv1w, cv1s, cv1b, cv2w, cv2s, cv2b, m1w, m1s, m1b, a, bbuf, y16);
    m2cv3_kernel<<<NTILE2, 512, 0, stream>>>(
        y16, a, bbuf, m2w, m2s, m2b, cv3w, cv3s, cv3b, (float*)d_out);
}